// Round 3
// baseline (225.303 us; speedup 1.0000x reference)
//
#include <hip/hip_runtime.h>
#include <math.h>

// ---------------- types / helpers ----------------
typedef float f32x4 __attribute__((ext_vector_type(4)));
typedef __bf16 bf16x8 __attribute__((ext_vector_type(8)));
typedef unsigned short ushort_t;

#define MFMA16(a, b, c) __builtin_amdgcn_mfma_f32_16x16x32_bf16((a), (b), (c), 0, 0, 0)

static __device__ __forceinline__ ushort_t f2bf(float f) {
  union { float f; unsigned u; } v; v.f = f;
  unsigned u = v.u;
  return (ushort_t)((u + 0x7FFFu + ((u >> 16) & 1u)) >> 16);  // RNE
}
// async global->LDS, 16B per lane; lds pointer must be wave-uniform (dest = base + lane*16)
static __device__ __forceinline__ void gl_lds16(const void* g, void* lds_uniform) {
  __builtin_amdgcn_global_load_lds(
      (const __attribute__((address_space(1))) unsigned int*)g,
      (__attribute__((address_space(3))) unsigned int*)lds_uniform, 16, 0, 0);
}

// ---------------- fused prep: RoPE table first (fp64 sincos overlaps casts) ----------
// blocks [0,512): rope table 4096*32; [512,8704): x cast; [8704,12800): 4 weights.
__global__ void prep(const float* __restrict__ x,
                     const float* __restrict__ wq, const float* __restrict__ wk,
                     const float* __restrict__ wv, const float* __restrict__ wo,
                     ushort_t* __restrict__ Xb, ushort_t* __restrict__ Wqb,
                     ushort_t* __restrict__ Wkb, ushort_t* __restrict__ Wvb,
                     ushort_t* __restrict__ Wob, float2* __restrict__ cs) {
  const int bid = blockIdx.x;
  if (bid < 512) {
    int idx = bid * 256 + threadIdx.x;  // 4096*32 entries
    int pos = idx >> 5, i = idx & 31;
    double inv = exp2(-(double)i * 0.41524101186092029);  // log2(10000)/32
    double th = (double)pos * inv;
    double s, c;
    sincos(th, &s, &c);
    cs[idx] = make_float2((float)c, (float)s);
  } else {
    const float* src;
    ushort_t* dst;
    int i;
    if (bid < 8704) {
      src = x; dst = Xb;
      i = (bid - 512) * 256 + threadIdx.x;
    } else {
      const int wi = (bid - 8704) >> 10;
      src = (wi == 0) ? wq : (wi == 1) ? wk : (wi == 2) ? wv : wo;
      dst = (wi == 0) ? Wqb : (wi == 1) ? Wkb : (wi == 2) ? Wvb : Wob;
      i = ((bid - 8704) & 1023) * 256 + threadIdx.x;
    }
    f32x4 v = ((const f32x4*)src)[i];
    ushort4 o;
    o.x = f2bf(v.x); o.y = f2bf(v.y); o.z = f2bf(v.z); o.w = f2bf(v.w);
    ((ushort4*)dst)[i] = o;
  }
}

// ---------------- NT GEMM, BK=64, XOR-swizzled LDS; optional fused RoPE epilogue -----
// C[m][n] = sum_k A[m][k]*W[n][k]. A: MxK bf16 rm, W: NxK bf16 rm.
// ROPE=1: z=0 -> rope * 0.125 (Q), z=1 -> rope (K), z=2 -> plain (V). pos = row&4095,
// pair index = (col&63)>>1; lane pairs (l15 even/odd) exchanged via shfl_xor(.,1).
template <int OUTBF, int ROPE>
__global__ __launch_bounds__(256) void gemm_nt(
    const ushort_t* __restrict__ A,
    const ushort_t* __restrict__ W0, const ushort_t* __restrict__ W1, const ushort_t* __restrict__ W2,
    void* __restrict__ C0, void* __restrict__ C1, void* __restrict__ C2,
    int K, int N, const float2* __restrict__ cs) {
  __shared__ __align__(16) ushort_t As[128 * 64];
  __shared__ __align__(16) ushort_t Bs[128 * 64];
  const int z = blockIdx.z;
  const ushort_t* W = (z == 0) ? W0 : (z == 1 ? W1 : W2);
  void* Cv = (z == 0) ? C0 : (z == 1 ? C1 : C2);

  const int t = threadIdx.x;
  const int lane = t & 63;
  const int l15 = lane & 15;
  const int quad = lane >> 4;
  const int wave = t >> 6;
  const int wm = wave & 1, wn = wave >> 1;
  const int bm = blockIdx.x, bn = blockIdx.y;

  // staging: thread t -> row t>>3, LDS chunk t&7, global chunk (t&7)^(row&7)
  const int srow = t >> 3;
  const int schunk = (t & 7) ^ (srow & 7);
  const ushort_t* Ag = A + (size_t)(bm * 128 + srow) * K + schunk * 8;
  const ushort_t* Wg = W + (size_t)(bn * 128 + srow) * K + schunk * 8;
  char* AsB = (char*)As + (t & 192) * 16;  // wave-uniform; lane slot = base + lane*16
  char* BsB = (char*)Bs + (t & 192) * 16;
  const size_t rK = (size_t)32 * K;

  const f32x4 zero4 = {0.f, 0.f, 0.f, 0.f};
  f32x4 acc[4][4];
#pragma unroll
  for (int i = 0; i < 4; ++i)
#pragma unroll
    for (int j = 0; j < 4; ++j) acc[i][j] = zero4;

  for (int kt = 0; kt < K; kt += 64) {
#pragma unroll
    for (int p = 0; p < 4; ++p) {
      gl_lds16(Ag + p * rK + kt, AsB + p * 4096);
      gl_lds16(Wg + p * rK + kt, BsB + p * 4096);
    }
    __syncthreads();
#pragma unroll
    for (int ks = 0; ks < 2; ++ks) {
      bf16x8 af[4], bfr[4];
#pragma unroll
      for (int i = 0; i < 4; ++i) {
        const int r = wm * 64 + i * 16 + l15;
        af[i] = *(const bf16x8*)&As[r * 64 + (((ks * 4 + quad) ^ (r & 7)) * 8)];
      }
#pragma unroll
      for (int j = 0; j < 4; ++j) {
        const int r = wn * 64 + j * 16 + l15;
        bfr[j] = *(const bf16x8*)&Bs[r * 64 + (((ks * 4 + quad) ^ (r & 7)) * 8)];
      }
#pragma unroll
      for (int i = 0; i < 4; ++i)
#pragma unroll
        for (int j = 0; j < 4; ++j) acc[i][j] = MFMA16(af[i], bfr[j], acc[i][j]);
    }
    __syncthreads();
  }

  const int rbase = bm * 128 + wm * 64 + quad * 4;
  const int cbase = bn * 128 + wn * 64 + l15;

  if (ROPE && z < 2) {
    const float qsc = (z == 0) ? 0.125f : 1.0f;
#pragma unroll
    for (int i = 0; i < 4; ++i)
#pragma unroll
      for (int j = 0; j < 4; ++j) {
        const int ipair = (((j & 3) * 16 + l15) & 63) >> 1;
#pragma unroll
        for (int r = 0; r < 4; ++r) {
          const int pos = (rbase + i * 16 + r) & 4095;
          float2 sc = cs[pos * 32 + ipair];
          float v = acc[i][j][r];
          float p = __shfl_xor(v, 1);
          float sg = (l15 & 1) ? sc.y : -sc.y;
          acc[i][j][r] = (v * sc.x + p * sg) * qsc;
        }
      }
  }

#pragma unroll
  for (int i = 0; i < 4; ++i)
#pragma unroll
    for (int j = 0; j < 4; ++j)
#pragma unroll
      for (int r = 0; r < 4; ++r) {
        size_t idx = (size_t)(rbase + i * 16 + r) * N + (cbase + j * 16);
        if (OUTBF)
          ((ushort_t*)Cv)[idx] = f2bf(acc[i][j][r]);
        else
          ((float*)Cv)[idx] = acc[i][j][r];
      }
}

// ---------------- fused windowed attention (Q/K pre-roped by GEMM) ----------------
// grid = (64, 16, 2): x = win*4 + quarter, y = head, z = batch. 256 threads / 4 waves.
// Each wave: 16 q-rows x 256 keys -> S[16] f32x4 (64 regs). 3 barriers total.
__global__ __launch_bounds__(256, 3) void attn(
    const ushort_t* __restrict__ Qb, const ushort_t* __restrict__ Kb,
    const ushort_t* __restrict__ Vb, ushort_t* __restrict__ Yb) {
  // 43008 B LDS, overlaid: phase A: Ks[256][72] @0; phase B: Vt[64][264] @0, Pc[64][72] @33792B
  __shared__ __align__(16) ushort_t smem[21504];
  ushort_t* Ks = smem;
  ushort_t* Vt = smem;
  ushort_t* Pc = smem + 16896;

  const int t = threadIdx.x;
  const int lane = t & 63, wave = t >> 6;
  const int l15 = lane & 15, quad = lane >> 4;
  const int win = blockIdx.x >> 2, qq = blockIdx.x & 3;
  const int h = blockIdx.y, b = blockIdx.z;
  const int kBase = win * 256;
  const int qRow0 = kBase + qq * 64 + wave * 16;  // this wave's first q row
  const size_t gbase = ((size_t)b * 4096) * 1024 + h * 64;

  const int sr = t >> 3;       // 0..31
  const int c0 = (t & 7) * 8;  // 0..56

  // ---- stage K (already roped) ----
#pragma unroll
  for (int p = 0; p < 8; ++p) {
    int r = p * 32 + sr;
    *(uint4*)&Ks[r * 72 + c0] =
        *(const uint4*)(Kb + gbase + (size_t)(kBase + r) * 1024 + c0);
  }
  __syncthreads();

  // ---- QK^T: S[16 q x 256 k] per wave; Q A-frags direct from global ----
  const f32x4 zero4 = {0.f, 0.f, 0.f, 0.f};
  f32x4 S[16];
#pragma unroll
  for (int j = 0; j < 16; ++j) S[j] = zero4;
#pragma unroll
  for (int ks = 0; ks < 2; ++ks) {
    bf16x8 a = *(const bf16x8*)(Qb + gbase + (size_t)(qRow0 + l15) * 1024 + ks * 32 + quad * 8);
#pragma unroll
    for (int j = 0; j < 16; ++j) {
      bf16x8 bk = *(const bf16x8*)&Ks[(j * 16 + l15) * 72 + ks * 32 + quad * 8];
      S[j] = MFMA16(a, bk, S[j]);
    }
  }

  // ---- softmax (fp32; row m = quad*4+r, cols = j*16 + l15) ----
  float linv[4];
#pragma unroll
  for (int r = 0; r < 4; ++r) {
    float mx = S[0][r];
#pragma unroll
    for (int j = 1; j < 16; ++j) mx = fmaxf(mx, S[j][r]);
    mx = fmaxf(mx, __shfl_xor(mx, 1));
    mx = fmaxf(mx, __shfl_xor(mx, 2));
    mx = fmaxf(mx, __shfl_xor(mx, 4));
    mx = fmaxf(mx, __shfl_xor(mx, 8));
    float sum = 0.f;
#pragma unroll
    for (int j = 0; j < 16; ++j) {
      float e = __expf(S[j][r] - mx);
      S[j][r] = e;
      sum += e;
    }
    sum += __shfl_xor(sum, 1);
    sum += __shfl_xor(sum, 2);
    sum += __shfl_xor(sum, 4);
    sum += __shfl_xor(sum, 8);
    linv[r] = 1.0f / sum;
  }
  __syncthreads();  // done reading Ks; overlay becomes Vt

  // ---- stage V transposed: Vt[d][k], lane-staggered (conflict-free) ----
#pragma unroll
  for (int p = 0; p < 8; ++p) {
    int k = p * 32 + sr;
    uint4 raw = *(const uint4*)(Vb + gbase + (size_t)(kBase + k) * 1024 + c0);
    ushort_t vv[8];
    vv[0] = raw.x & 0xffffu; vv[1] = raw.x >> 16;
    vv[2] = raw.y & 0xffffu; vv[3] = raw.y >> 16;
    vv[4] = raw.z & 0xffffu; vv[5] = raw.z >> 16;
    vv[6] = raw.w & 0xffffu; vv[7] = raw.w >> 16;
#pragma unroll
    for (int e = 0; e < 8; ++e) {
      int ee = (e + (t & 7)) & 7;
      Vt[(c0 + ee) * 264 + k] = vv[ee];
    }
  }
  __syncthreads();  // Vt complete; Pc is wave-private below -> no more barriers

  // ---- PV with per-wave P chunks through LDS (C-layout -> A-layout) ----
  const int qw = wave * 16;
  f32x4 O[4];
#pragma unroll
  for (int jd = 0; jd < 4; ++jd) O[jd] = zero4;

#pragma unroll
  for (int kc = 0; kc < 4; ++kc) {
#pragma unroll
    for (int jj = 0; jj < 4; ++jj) {
      int j = kc * 4 + jj;
#pragma unroll
      for (int r = 0; r < 4; ++r)
        Pc[(qw + quad * 4 + r) * 72 + jj * 16 + l15] = f2bf(S[j][r]);
    }
#pragma unroll
    for (int ks = 0; ks < 2; ++ks) {
      bf16x8 a = *(const bf16x8*)&Pc[(qw + l15) * 72 + ks * 32 + quad * 8];
#pragma unroll
      for (int jd = 0; jd < 4; ++jd) {
        bf16x8 bv = *(const bf16x8*)&Vt[(jd * 16 + l15) * 264 + kc * 64 + ks * 32 + quad * 8];
        O[jd] = MFMA16(a, bv, O[jd]);
      }
    }
  }

  // ---- epilogue: normalize, write Y (B,T,C) bf16 ----
#pragma unroll
  for (int jd = 0; jd < 4; ++jd)
#pragma unroll
    for (int r = 0; r < 4; ++r) {
      int row = qRow0 + quad * 4 + r;
      Yb[gbase + (size_t)row * 1024 + jd * 16 + l15] = f2bf(O[jd][r] * linv[r]);
    }
}

// ---------------- launch ----------------
extern "C" void kernel_launch(void* const* d_in, const int* in_sizes, int n_in,
                              void* d_out, int out_size, void* d_ws, size_t ws_size,
                              hipStream_t stream) {
  (void)in_sizes; (void)n_in; (void)out_size; (void)ws_size;
  const float* x  = (const float*)d_in[0];
  const float* wq = (const float*)d_in[1];
  const float* wk = (const float*)d_in[2];
  const float* wv = (const float*)d_in[3];
  const float* wo = (const float*)d_in[4];

  char* ws = (char*)d_ws;
  // workspace layout (bytes): Xb 16M | Wq..Wo 4x2M | Qb 16M | Kb 16M | Vb 16M | Yb 16M | cs 1M
  ushort_t* Xb  = (ushort_t*)(ws);
  ushort_t* Wqb = (ushort_t*)(ws + 16777216);
  ushort_t* Wkb = Wqb + 1048576;
  ushort_t* Wvb = Wkb + 1048576;
  ushort_t* Wob = Wvb + 1048576;
  ushort_t* Qb  = (ushort_t*)(ws + 25165824);
  ushort_t* Kb  = Qb + 8388608;
  ushort_t* Vb  = Kb + 8388608;
  ushort_t* Yb  = Vb + 8388608;
  float2*   cs  = (float2*)(ws + 92274688);

  prep<<<dim3(12800), dim3(256), 0, stream>>>(x, wq, wk, wv, wo,
                                              Xb, Wqb, Wkb, Wvb, Wob, cs);

  gemm_nt<1, 1><<<dim3(64, 8, 3), dim3(256), 0, stream>>>(
      Xb, Wqb, Wkb, Wvb, (void*)Qb, (void*)Kb, (void*)Vb, 1024, 1024, cs);

  attn<<<dim3(64, 16, 2), dim3(256), 0, stream>>>(Qb, Kb, Vb, Yb);

  gemm_nt<0, 0><<<dim3(64, 8, 1), dim3(256), 0, stream>>>(
      Yb, Wob, Wob, Wob, d_out, d_out, d_out, 1024, 1024, nullptr);
}